// Round 3
// baseline (183.464 us; speedup 1.0000x reference)
//
#include <hip/hip_runtime.h>
#include <hip/hip_bf16.h>
#include <cstdint>

using bf16 = __hip_bfloat16;
typedef __attribute__((ext_vector_type(8))) short s8v;
typedef __attribute__((ext_vector_type(4))) float f32x4;

#define DEV static __device__ __forceinline__

DEV unsigned short f2b(float x) {
    __hip_bfloat16 h = __float2bfloat16(x);
    return __builtin_bit_cast(unsigned short, h);
}
DEV float sigm(float x) { return 1.0f / (1.0f + __expf(-x)); }

DEV void gload16(const void* g, void* l) {
    __builtin_amdgcn_global_load_lds(
        (const __attribute__((address_space(1))) uint32_t*)g,
        (__attribute__((address_space(3))) uint32_t*)l, 16, 0, 0);
}

// ---------------------------------------------------------------------------
// Big GEMM: C = A (MxK row-major) * B^T (B NxK row-major), 256x256 tile,
// BK=32, 8 waves (2x4), wave-tile 128x64, ring-4 LDS (128KB), counted vmcnt,
// ONE barrier per K-step. LDS layout per tile: 128 lrows x 128B, logical
// (r,k) at lrow=r>>1, slot ls=(r&1)*4+(kbyte>>4), phys slot = ls^(lrow&7).
// Staging keeps LDS dest linear; global source is inverse-swizzled.
//  EPI 0: bf16 out = sigmoid(acc); also write masked row-sum partials
//  EPI 4: f32  out = (mask[row]&mask[col]) ? sigmoid(acc) : 0
// ---------------------------------------------------------------------------
template<int EPI>
__global__ __launch_bounds__(512)
void gemm256(const bf16* __restrict__ A, const bf16* __restrict__ B,
             void* __restrict__ C, const int M, const int N, const int K,
             const size_t sA, const size_t sB, const size_t sC,
             const int* __restrict__ mask, float* __restrict__ part)
{
    __shared__ bf16 sm[4][2][8192];   // ring4 x (A,B) x 16KB = 128KB
    const int b = blockIdx.z;
    const char* Ab = (const char*)(A + (size_t)b * sA);
    const char* Bb = (const char*)(B + (size_t)b * sB);
    const int bm = blockIdx.x * 256, bn = blockIdx.y * 256;
    const int tid = threadIdx.x, lane = tid & 63, wv = tid >> 6;
    const int wr = wv >> 2, wc = wv & 3;
    const int fr = lane & 15, fq = lane >> 4;
    const size_t lda = (size_t)K * 2;
    char* smb = (char*)&sm[0][0][0];

    // staging: 2 instrs for A, 2 for B; per-instr 512thr x 16B = 8KB
    size_t aO[2], bO[2];
    int ldsO[2];
#pragma unroll
    for (int i = 0; i < 2; ++i) {
        ldsO[i] = i * 8192 + wv * 1024;
        const int myOff = ldsO[i] + lane * 16;
        const int lrow = myOff >> 7;
        const int p = (myOff >> 4) & 7;
        const int ls = p ^ (lrow & 7);
        const int srow = lrow * 2 + (ls >> 2);
        const int scol = (ls & 3) * 16;
        aO[i] = (size_t)(bm + srow) * lda + scol;
        bO[i] = (size_t)(bn + srow) * lda + scol;
    }

    f32x4 acc[8][4];
#pragma unroll
    for (int m = 0; m < 8; ++m)
#pragma unroll
        for (int n = 0; n < 4; ++n)
            acc[m][n] = (f32x4){0.f, 0.f, 0.f, 0.f};

    auto STAGE = [&](int buf, int t) {
        const size_t kb = (size_t)t * 64;   // BK=32 bf16 = 64 bytes
        char* base = smb + buf * 32768;
#pragma unroll
        for (int i = 0; i < 2; ++i) {
            gload16(Ab + aO[i] + kb, base + ldsO[i]);
            gload16(Bb + bO[i] + kb, base + 16384 + ldsO[i]);
        }
    };

    // ds_read swizzled address for logical row r, k-slice fq (16B)
    auto lAddr = [&](int r) -> int {
        const int lrow = r >> 1;
        const int ls = (r & 1) * 4 + fq;
        const int ph = ls ^ (lrow & 7);
        return lrow * 128 + ph * 16;
    };

    auto COMPUTE = [&](int buf) {
        const char* sA_ = smb + buf * 32768;
        const char* sB_ = sA_ + 16384;
        s8v af[8], bfv[4];
#pragma unroll
        for (int m = 0; m < 8; ++m)
            af[m] = *(const s8v*)(sA_ + lAddr(wr * 128 + m * 16 + fr));
#pragma unroll
        for (int n = 0; n < 4; ++n)
            bfv[n] = *(const s8v*)(sB_ + lAddr(wc * 64 + n * 16 + fr));
#pragma unroll
        for (int m = 0; m < 8; ++m)
#pragma unroll
            for (int n = 0; n < 4; ++n)
                acc[m][n] = __builtin_amdgcn_mfma_f32_16x16x32_bf16(
                    af[m], bfv[n], acc[m][n], 0, 0, 0);
    };

    const int NT = K >> 5;
    STAGE(0, 0); STAGE(1, 1); STAGE(2, 2);
    for (int t = 0; t < NT; ++t) {
        if (t < NT - 2)       asm volatile("s_waitcnt vmcnt(8)" ::: "memory");
        else if (t == NT - 2) asm volatile("s_waitcnt vmcnt(4)" ::: "memory");
        else                  asm volatile("s_waitcnt vmcnt(0)" ::: "memory");
        __builtin_amdgcn_s_barrier();
        __builtin_amdgcn_sched_barrier(0);
        if (t + 3 < NT) STAGE((t + 3) & 3, t + 3);
        COMPUTE(t & 3);
    }

    // epilogue: C/D layout col = lane&15, row = (lane>>4)*4 + reg
    const int row0 = bm + wr * 128 + fq * 4;
    const int col0 = bn + wc * 64 + fr;
    if constexpr (EPI == 0) {
        int cm[4];
#pragma unroll
        for (int n = 0; n < 4; ++n) cm[n] = mask[(size_t)b * N + col0 + n * 16];
#pragma unroll
        for (int m = 0; m < 8; ++m) {
            float rs[4] = {0.f, 0.f, 0.f, 0.f};
#pragma unroll
            for (int n = 0; n < 4; ++n) {
                const int col = col0 + n * 16;
#pragma unroll
                for (int r = 0; r < 4; ++r) {
                    const int row = row0 + m * 16 + r;
                    const float x = sigm(acc[m][n][r]);
                    ((bf16*)C)[(size_t)b * sC + (size_t)row * N + col] =
                        __float2bfloat16(x);
                    if (cm[n]) rs[r] += x;
                }
            }
#pragma unroll
            for (int off = 1; off < 16; off <<= 1)
#pragma unroll
                for (int r = 0; r < 4; ++r) rs[r] += __shfl_xor(rs[r], off);
            if (fr == 0) {
#pragma unroll
                for (int r = 0; r < 4; ++r)
                    part[((size_t)b * M + row0 + m * 16 + r) * 32 +
                         blockIdx.y * 4 + wc] = rs[r];
            }
        }
    } else {
        int cm[4];
#pragma unroll
        for (int n = 0; n < 4; ++n) cm[n] = mask[(size_t)b * N + col0 + n * 16];
#pragma unroll
        for (int m = 0; m < 8; ++m) {
            int rm[4];
#pragma unroll
            for (int r = 0; r < 4; ++r)
                rm[r] = mask[(size_t)b * M + row0 + m * 16 + r];
#pragma unroll
            for (int n = 0; n < 4; ++n) {
                const int col = col0 + n * 16;
#pragma unroll
                for (int r = 0; r < 4; ++r) {
                    const int row = row0 + m * 16 + r;
                    ((float*)C)[(size_t)b * sC + (size_t)row * N + col] =
                        (rm[r] & cm[n]) ? sigm(acc[m][n][r]) : 0.0f;
                }
            }
        }
    }
}

// ---------------------------------------------------------------------------
// Small/medium GEMM (unchanged proven 128x128 2-phase template).
//  1: bf16 out = mask[row] ? d[row]*(acc + d[row]*Xres[row,col]) : 0   (agg)
//  2: bf16 out = relu(acc + bias[col])
//  3: bf16 out = acc + bias[col]
// ---------------------------------------------------------------------------
template<int EPI>
__global__ __launch_bounds__(256)
void gemm_bt(const bf16* __restrict__ A, const bf16* __restrict__ B,
             void* __restrict__ C, const int M, const int N, const int K,
             const size_t sA, const size_t sB, const size_t sC,
             const float* __restrict__ Xres, const float* __restrict__ dval,
             const int* __restrict__ mask, const float* __restrict__ bias)
{
    __shared__ bf16 sm[2][2][128 * 64];
    const int b = blockIdx.z;
    const char* Ab = (const char*)(A + (size_t)b * sA);
    const char* Bb = (const char*)(B + (size_t)b * sB);
    const int bm = blockIdx.x * 128;
    const int bn = blockIdx.y * 128;
    const int tid = threadIdx.x;
    const int lane = tid & 63;
    const int wv = tid >> 6;
    const int wr = wv >> 1, wc = wv & 1;
    const int fr = lane & 15, fq = lane >> 4;
    const size_t lda = (size_t)K * 2;

    size_t aOff[4], bOff[4];
    int ldsO[4];
#pragma unroll
    for (int i = 0; i < 4; ++i) {
        const int ldsOff = i * 4096 + wv * 1024;
        const int myOff = ldsOff + lane * 16;
        const int row = myOff >> 7;
        const int lc = (myOff & 127) ^ ((row & 7) << 4);
        ldsO[i] = ldsOff;
        aOff[i] = (size_t)(bm + row) * lda + lc;
        bOff[i] = (size_t)(bn + row) * lda + lc;
    }

    f32x4 acc[4][4];
#pragma unroll
    for (int m = 0; m < 4; ++m)
#pragma unroll
        for (int n = 0; n < 4; ++n)
            acc[m][n] = (f32x4){0.f, 0.f, 0.f, 0.f};

    char* smb = (char*)&sm[0][0][0];

    auto STAGE = [&](int buf, size_t kb) {
#pragma unroll
        for (int i = 0; i < 4; ++i) {
            gload16(Ab + aOff[i] + kb, smb + buf * 32768 + ldsO[i]);
            gload16(Bb + bOff[i] + kb, smb + buf * 32768 + 16384 + ldsO[i]);
        }
    };

    auto COMPUTE = [&](int buf) {
#pragma unroll
        for (int kk = 0; kk < 2; ++kk) {
            s8v af[4], bfv[4];
#pragma unroll
            for (int m = 0; m < 4; ++m) {
                const int r = wr * 64 + m * 16 + fr;
                const int pb = (r << 7) | ((kk * 64 + fq * 16) ^ ((r & 7) << 4));
                af[m] = *(const s8v*)(smb + buf * 32768 + pb);
            }
#pragma unroll
            for (int n = 0; n < 4; ++n) {
                const int r = wc * 64 + n * 16 + fr;
                const int pb = (r << 7) | ((kk * 64 + fq * 16) ^ ((r & 7) << 4));
                bfv[n] = *(const s8v*)(smb + buf * 32768 + 16384 + pb);
            }
#pragma unroll
            for (int m = 0; m < 4; ++m)
#pragma unroll
                for (int n = 0; n < 4; ++n)
                    acc[m][n] = __builtin_amdgcn_mfma_f32_16x16x32_bf16(
                        af[m], bfv[n], acc[m][n], 0, 0, 0);
        }
    };

    const int NT = K >> 6;
    STAGE(0, 0);
    asm volatile("s_waitcnt vmcnt(0)" ::: "memory");
    __syncthreads();
    int cur = 0;
    for (int t = 0; t < NT - 1; ++t) {
        STAGE(cur ^ 1, (size_t)(t + 1) * 128);
        COMPUTE(cur);
        asm volatile("s_waitcnt vmcnt(0)" ::: "memory");
        __syncthreads();
        cur ^= 1;
    }
    COMPUTE(cur);

    const int row0 = bm + wr * 64 + fq * 4;
    const int col0 = bn + wc * 64 + fr;
#pragma unroll
    for (int m = 0; m < 4; ++m) {
#pragma unroll
        for (int n = 0; n < 4; ++n) {
            const int col = col0 + n * 16;
#pragma unroll
            for (int r = 0; r < 4; ++r) {
                const int row = row0 + m * 16 + r;
                const float x = acc[m][n][r];
                const size_t cidx = (size_t)b * sC + (size_t)row * N + col;
                if constexpr (EPI == 1) {
                    const float dn = dval[(size_t)b * M + row];
                    const int mn = mask[(size_t)b * M + row];
                    const float xv = Xres[(size_t)b * M * N + (size_t)row * N + col];
                    ((bf16*)C)[cidx] = __float2bfloat16(mn ? dn * (x + dn * xv) : 0.0f);
                } else if constexpr (EPI == 2) {
                    ((bf16*)C)[cidx] = __float2bfloat16(fmaxf(x + bias[col], 0.0f));
                } else {
                    ((bf16*)C)[cidx] = __float2bfloat16(x + bias[col]);
                }
            }
        }
    }
}

// ---------------------------------------------------------------------------
// Row-normalize X (f32 [B*N,256]) -> Xn (bf16). One wave per row.
// ---------------------------------------------------------------------------
__global__ __launch_bounds__(256)
void xn_kernel(const float* __restrict__ X, bf16* __restrict__ Xn)
{
    const int lane = threadIdx.x & 63;
    const size_t row = (size_t)blockIdx.x * 4 + (threadIdx.x >> 6);
    const float4 v = *(const float4*)&X[row * 256 + lane * 4];
    float ss = v.x * v.x + v.y * v.y + v.z * v.z + v.w * v.w;
#pragma unroll
    for (int o = 32; o; o >>= 1) ss += __shfl_xor(ss, o);
    const float inv = 1.0f / fmaxf(sqrtf(ss), 1e-12f);
    ushort4 o4;
    o4.x = f2b(v.x * inv); o4.y = f2b(v.y * inv);
    o4.z = f2b(v.z * inv); o4.w = f2b(v.w * inv);
    *(ushort4*)&Xn[row * 256 + lane * 4] = o4;
}

// ---------------------------------------------------------------------------
// Finalize degree: dvl[row] = rsqrt(max(mask[row]*(sum(part[row,:])+1),1e-6)).
// One wave per row (32 slots). row = b*2048+n (mask is flat the same way).
// ---------------------------------------------------------------------------
__global__ __launch_bounds__(256)
void fin_deg(const float* __restrict__ part, const int* __restrict__ mask,
             float* __restrict__ dvl)
{
    const int lane = threadIdx.x & 63;
    const int row = blockIdx.x * 4 + (threadIdx.x >> 6);
    float v = (lane < 32) ? part[(size_t)row * 32 + lane] : 0.0f;
#pragma unroll
    for (int o = 32; o; o >>= 1) v += __shfl_xor(v, o);
    if (lane == 0) {
        const float deg = mask[row] ? (v + 1.0f) : 0.0f;
        dvl[row] = rsqrtf(fmaxf(deg, 1e-6f));
    }
}

// ---------------------------------------------------------------------------
// Yt[b][d][m] = bf16( (mask[m] ? dval[m] : 0) * X[b][m][d] )
// ---------------------------------------------------------------------------
__global__ __launch_bounds__(256)
void yt_kernel(const float* __restrict__ X, const float* __restrict__ dval,
               const int* __restrict__ mask, bf16* __restrict__ Yt)
{
    __shared__ float tile[64][65];
    const int b = blockIdx.z;
    const int m0 = blockIdx.x * 64, d0 = blockIdx.y * 64;
    const float* Xb = X + (size_t)b * 2048 * 256;
    const float* dv = dval + (size_t)b * 2048;
    const int* mk = mask + (size_t)b * 2048;
    const int t = threadIdx.x;
    const int ml = t >> 4;
    const int dl4 = (t & 15) * 4;
#pragma unroll
    for (int i = 0; i < 4; ++i) {
        const int m = ml + i * 16;
        const int gm = m0 + m;
        const float sd = mk[gm] ? dv[gm] : 0.0f;
        const float4 v = *(const float4*)&Xb[(size_t)gm * 256 + d0 + dl4];
        tile[m][dl4 + 0] = v.x * sd; tile[m][dl4 + 1] = v.y * sd;
        tile[m][dl4 + 2] = v.z * sd; tile[m][dl4 + 3] = v.w * sd;
    }
    __syncthreads();
    bf16* Yb = Yt + (size_t)b * 256 * 2048;
    const int dl = t >> 4;
    const int ml4 = (t & 15) * 4;
#pragma unroll
    for (int i = 0; i < 4; ++i) {
        const int d = dl + i * 16;
        ushort4 o;
        o.x = f2b(tile[ml4 + 0][d]);
        o.y = f2b(tile[ml4 + 1][d]);
        o.z = f2b(tile[ml4 + 2][d]);
        o.w = f2b(tile[ml4 + 3][d]);
        *(ushort4*)&Yb[(size_t)(d0 + d) * 2048 + m0 + ml4] = o;
    }
}

// ---------------------------------------------------------------------------
// Transpose both weight matrices to bf16.
// ---------------------------------------------------------------------------
__global__ __launch_bounds__(256)
void prep_w(const float* __restrict__ W1, const float* __restrict__ W2,
            bf16* __restrict__ W1t, bf16* __restrict__ W2t)
{
    const int idx = blockIdx.x * 256 + threadIdx.x;
    const int h = idx & 255, d = idx >> 8;
    W1t[h * 256 + d] = __float2bfloat16(W1[idx]);
    W2t[h * 256 + d] = __float2bfloat16(W2[idx]);
}

extern "C" void kernel_launch(void* const* d_in, const int* in_sizes, int n_in,
                              void* d_out, int out_size, void* d_ws, size_t ws_size,
                              hipStream_t stream)
{
    (void)in_sizes; (void)n_in; (void)out_size; (void)ws_size;
    const float* X  = (const float*)d_in[0];
    const int*  msk = (const int*)d_in[1];
    const float* W1 = (const float*)d_in[2];
    const float* b1 = (const float*)d_in[3];
    const float* W2 = (const float*)d_in[4];
    const float* b2 = (const float*)d_in[5];

    // scratch inside d_out (134,217,728 B), all dead before the final GEMM:
    char* O = (char*)d_out;
    bf16* S    = (bf16*)(O);                 // 67,108,864 B  [8][2048][2048]
    bf16* Xn   = (bf16*)(O + 67108864);      //  8,388,608 B  [8][2048][256]
    bf16* Yt   = (bf16*)(O + 75497472);      //  8,388,608 B  [8][256][2048]
    bf16* agg  = (bf16*)(O + 83886080);      //  8,388,608 B  [8][2048][256]
    bf16* Hf   = (bf16*)(O + 92274688);      //  8,388,608 B  [16384][256]
    float* dvl = (float*)(O + 100663296);    //     65,536 B  [8][2048]
    bf16* W1t  = (bf16*)(O + 100728832);     //    131,072 B
    bf16* W2t  = (bf16*)(O + 100859904);     //    131,072 B
    float* part= (float*)(O + 100990976);    //  2,097,152 B  [8][2048][32]
    bf16* P    = (bf16*)d_ws;                //  8,388,608 B  (survives final GEMM)

    prep_w<<<256, 256, 0, stream>>>(W1, W2, W1t, W2t);
    xn_kernel<<<4096, 256, 0, stream>>>(X, Xn);

    // S = sigmoid(Xn Xn^T) bf16, + masked row-sum partials
    gemm256<0><<<dim3(8, 8, 8), 512, 0, stream>>>(
        Xn, Xn, S, 2048, 2048, 256,
        (size_t)2048 * 256, (size_t)2048 * 256, (size_t)2048 * 2048,
        msk, part);

    fin_deg<<<4096, 256, 0, stream>>>(part, msk, dvl);
    yt_kernel<<<dim3(32, 4, 8), 256, 0, stream>>>(X, dvl, msk, Yt);

    // agg = m d (S @ Y + d X), bf16
    gemm_bt<1><<<dim3(16, 2, 8), 256, 0, stream>>>(
        S, Yt, agg, 2048, 256, 2048,
        (size_t)2048 * 2048, (size_t)256 * 2048, (size_t)2048 * 256,
        X, dvl, msk, nullptr);

    // Hf = relu(agg @ W1 + b1)
    gemm_bt<2><<<dim3(128, 2, 1), 256, 0, stream>>>(
        agg, W1t, Hf, 16384, 256, 256, 0, 0, 0,
        nullptr, nullptr, nullptr, b1);

    // P = Hf @ W2 + b2
    gemm_bt<3><<<dim3(128, 2, 1), 256, 0, stream>>>(
        Hf, W2t, P, 16384, 256, 256, 0, 0, 0,
        nullptr, nullptr, nullptr, b2);

    // out = mask_r * mask_c * sigmoid(P P^T), f32
    gemm256<4><<<dim3(8, 8, 8), 512, 0, stream>>>(
        P, P, d_out, 2048, 2048, 256,
        (size_t)2048 * 256, (size_t)2048 * 256, (size_t)2048 * 2048,
        msk, nullptr);
}

// Round 4
// 154.958 us; speedup vs baseline: 1.1840x; 1.1840x over previous
//
#include <hip/hip_runtime.h>
#include <hip/hip_bf16.h>
#include <cstdint>

using bf16 = __hip_bfloat16;
typedef __attribute__((ext_vector_type(8))) short s8v;
typedef __attribute__((ext_vector_type(4))) float f32x4;

#define DEV static __device__ __forceinline__

DEV float b2f(unsigned short u) {
    union { float f; unsigned int i; } w; w.i = ((unsigned int)u) << 16; return w.f;
}
DEV unsigned short f2b(float x) {
    __hip_bfloat16 h = __float2bfloat16(x);
    return __builtin_bit_cast(unsigned short, h);
}
DEV float sigm(float x) { return 1.0f / (1.0f + __expf(-x)); }

DEV void gload16(const void* g, void* l) {
    __builtin_amdgcn_global_load_lds(
        (const __attribute__((address_space(1))) uint32_t*)g,
        (__attribute__((address_space(3))) uint32_t*)l, 16, 0, 0);
}

// ---------------------------------------------------------------------------
// bf16 GEMM, C = A (MxK row-major) * B^T (B NxK row-major). 128x128 tile,
// BK=64, 4 waves (2x2), 16x16x32 MFMA, 2-phase dbuf LDS, XOR swizzle
// (phys = logical ^ ((row&7)<<4)) with inverse-swizzled global staging src.
// Epilogues:
//  0: bf16 out = sigmoid(acc); + masked row-sum partials -> part[row][by*2+wc]
//  1: bf16 out = mask[row] ? d[row]*(acc + Yres[row,col]) : 0      (agg)
//  2: bf16 out = relu(acc + bias[col])
//  3: bf16 out = acc + bias[col]
//  4: f32  out = (mask[row]&mask[col]) ? sigmoid(acc) : 0
// ---------------------------------------------------------------------------
template<int EPI>
__global__ __launch_bounds__(256)
void gemm_bt(const bf16* __restrict__ A, const bf16* __restrict__ B,
             void* __restrict__ C, const int M, const int N, const int K,
             const size_t sA, const size_t sB, const size_t sC,
             const bf16* __restrict__ Yres, const float* __restrict__ dval,
             const int* __restrict__ mask, const float* __restrict__ bias,
             float* __restrict__ part)
{
    __shared__ bf16 sm[2][2][128 * 64];
    const int b = blockIdx.z;
    const char* Ab = (const char*)(A + (size_t)b * sA);
    const char* Bb = (const char*)(B + (size_t)b * sB);
    const int bm = blockIdx.x * 128;
    const int bn = blockIdx.y * 128;
    const int tid = threadIdx.x;
    const int lane = tid & 63;
    const int wv = tid >> 6;
    const int wr = wv >> 1, wc = wv & 1;
    const int fr = lane & 15, fq = lane >> 4;
    const size_t lda = (size_t)K * 2;

    size_t aOff[4], bOff[4];
    int ldsO[4];
#pragma unroll
    for (int i = 0; i < 4; ++i) {
        const int ldsOff = i * 4096 + wv * 1024;
        const int myOff = ldsOff + lane * 16;
        const int row = myOff >> 7;
        const int lc = (myOff & 127) ^ ((row & 7) << 4);
        ldsO[i] = ldsOff;
        aOff[i] = (size_t)(bm + row) * lda + lc;
        bOff[i] = (size_t)(bn + row) * lda + lc;
    }

    f32x4 acc[4][4];
#pragma unroll
    for (int m = 0; m < 4; ++m)
#pragma unroll
        for (int n = 0; n < 4; ++n)
            acc[m][n] = (f32x4){0.f, 0.f, 0.f, 0.f};

    char* smb = (char*)&sm[0][0][0];

    auto STAGE = [&](int buf, size_t kb) {
#pragma unroll
        for (int i = 0; i < 4; ++i) {
            gload16(Ab + aOff[i] + kb, smb + buf * 32768 + ldsO[i]);
            gload16(Bb + bOff[i] + kb, smb + buf * 32768 + 16384 + ldsO[i]);
        }
    };

    auto COMPUTE = [&](int buf) {
#pragma unroll
        for (int kk = 0; kk < 2; ++kk) {
            s8v af[4], bfv[4];
#pragma unroll
            for (int m = 0; m < 4; ++m) {
                const int r = wr * 64 + m * 16 + fr;
                const int pb = (r << 7) | ((kk * 64 + fq * 16) ^ ((r & 7) << 4));
                af[m] = *(const s8v*)(smb + buf * 32768 + pb);
            }
#pragma unroll
            for (int n = 0; n < 4; ++n) {
                const int r = wc * 64 + n * 16 + fr;
                const int pb = (r << 7) | ((kk * 64 + fq * 16) ^ ((r & 7) << 4));
                bfv[n] = *(const s8v*)(smb + buf * 32768 + 16384 + pb);
            }
#pragma unroll
            for (int m = 0; m < 4; ++m)
#pragma unroll
                for (int n = 0; n < 4; ++n)
                    acc[m][n] = __builtin_amdgcn_mfma_f32_16x16x32_bf16(
                        af[m], bfv[n], acc[m][n], 0, 0, 0);
        }
    };

    const int NT = K >> 6;
    STAGE(0, 0);
    asm volatile("s_waitcnt vmcnt(0)" ::: "memory");
    __syncthreads();
    int cur = 0;
    for (int t = 0; t < NT - 1; ++t) {
        STAGE(cur ^ 1, (size_t)(t + 1) * 128);
        COMPUTE(cur);
        asm volatile("s_waitcnt vmcnt(0)" ::: "memory");
        __syncthreads();
        cur ^= 1;
    }
    COMPUTE(cur);

    // epilogue: C/D layout col = lane&15, row = (lane>>4)*4 + reg
    const int row0 = bm + wr * 64 + fq * 4;
    const int col0 = bn + wc * 64 + fr;

    if constexpr (EPI == 0) {
        int cm[4];
#pragma unroll
        for (int n = 0; n < 4; ++n) cm[n] = mask[(size_t)b * N + col0 + n * 16];
#pragma unroll
        for (int m = 0; m < 4; ++m) {
            float rs[4] = {0.f, 0.f, 0.f, 0.f};
#pragma unroll
            for (int n = 0; n < 4; ++n) {
                const int col = col0 + n * 16;
#pragma unroll
                for (int r = 0; r < 4; ++r) {
                    const int row = row0 + m * 16 + r;
                    const float x = sigm(acc[m][n][r]);
                    ((bf16*)C)[(size_t)b * sC + (size_t)row * N + col] =
                        __float2bfloat16(x);
                    if (cm[n]) rs[r] += x;
                }
            }
#pragma unroll
            for (int off = 1; off < 16; off <<= 1)
#pragma unroll
                for (int r = 0; r < 4; ++r) rs[r] += __shfl_xor(rs[r], off);
            if (fr == 0) {
#pragma unroll
                for (int r = 0; r < 4; ++r)
                    part[((size_t)b * M + row0 + m * 16 + r) * 32 +
                         blockIdx.y * 2 + wc] = rs[r];
            }
        }
        return;
    }

#pragma unroll
    for (int m = 0; m < 4; ++m) {
#pragma unroll
        for (int n = 0; n < 4; ++n) {
            const int col = col0 + n * 16;
#pragma unroll
            for (int r = 0; r < 4; ++r) {
                const int row = row0 + m * 16 + r;
                const float x = acc[m][n][r];
                const size_t cidx = (size_t)b * sC + (size_t)row * N + col;
                if constexpr (EPI == 1) {
                    const float dn = dval[(size_t)b * M + row];
                    const int mn = mask[(size_t)b * M + row];
                    const float yv =
                        b2f(__builtin_bit_cast(unsigned short,
                            Yres[(size_t)b * M * N + (size_t)row * N + col]));
                    ((bf16*)C)[cidx] = __float2bfloat16(mn ? dn * (x + yv) : 0.0f);
                } else if constexpr (EPI == 2) {
                    ((bf16*)C)[cidx] = __float2bfloat16(fmaxf(x + bias[col], 0.0f));
                } else if constexpr (EPI == 3) {
                    ((bf16*)C)[cidx] = __float2bfloat16(x + bias[col]);
                } else {
                    const int mr = mask[(size_t)b * M + row];
                    const int mc = mask[(size_t)b * M + col];
                    ((float*)C)[cidx] = (mr & mc) ? sigm(x) : 0.0f;
                }
            }
        }
    }
}

// ---------------------------------------------------------------------------
// Row-normalize X (f32 [B*N,256]) -> Xn (bf16) + store rnorm = max(||X||,eps).
// One wave per row.
// ---------------------------------------------------------------------------
__global__ __launch_bounds__(256)
void xn_kernel(const float* __restrict__ X, bf16* __restrict__ Xn,
               float* __restrict__ rnorm)
{
    const int lane = threadIdx.x & 63;
    const size_t row = (size_t)blockIdx.x * 4 + (threadIdx.x >> 6);
    const float4 v = *(const float4*)&X[row * 256 + lane * 4];
    float ss = v.x * v.x + v.y * v.y + v.z * v.z + v.w * v.w;
#pragma unroll
    for (int o = 32; o; o >>= 1) ss += __shfl_xor(ss, o);
    const float nrm = fmaxf(sqrtf(ss), 1e-12f);
    const float inv = 1.0f / nrm;
    ushort4 o4;
    o4.x = f2b(v.x * inv); o4.y = f2b(v.y * inv);
    o4.z = f2b(v.z * inv); o4.w = f2b(v.w * inv);
    *(ushort4*)&Xn[row * 256 + lane * 4] = o4;
    if (lane == 0) rnorm[row] = nrm;
}

// ---------------------------------------------------------------------------
// dvl[row] = rsqrt(max(mask[row]*(sum32(part[row])+1), 1e-6)). Wave per row.
// ---------------------------------------------------------------------------
__global__ __launch_bounds__(256)
void fin_deg(const float* __restrict__ part, const int* __restrict__ mask,
             float* __restrict__ dvl)
{
    const int lane = threadIdx.x & 63;
    const int row = blockIdx.x * 4 + (threadIdx.x >> 6);
    float v = (lane < 32) ? part[(size_t)row * 32 + lane] : 0.0f;
#pragma unroll
    for (int o = 32; o; o >>= 1) v += __shfl_xor(v, o);
    if (lane == 0) {
        const float deg = mask[row] ? (v + 1.0f) : 0.0f;
        dvl[row] = rsqrtf(fmaxf(deg, 1e-6f));
    }
}

// ---------------------------------------------------------------------------
// From Xn (bf16) + rnorm: scale s = mask ? dvl*rnorm : 0, emit
//   Y [b][m][d] = bf16(s * Xn)            (straight, coalesced)
//   Yt[b][d][m] = bf16(s * Xn)            (transpose via LDS f32 tile)
// 64x64 tiles, 256 threads.
// ---------------------------------------------------------------------------
__global__ __launch_bounds__(256)
void ytY_kernel(const bf16* __restrict__ Xn, const float* __restrict__ rnorm,
                const float* __restrict__ dvl, const int* __restrict__ mask,
                bf16* __restrict__ Y, bf16* __restrict__ Yt)
{
    __shared__ float tile[64][65];
    const int b = blockIdx.z;
    const int m0 = blockIdx.x * 64, d0 = blockIdx.y * 64;
    const bf16* Xb = Xn + (size_t)b * 2048 * 256;
    const int t = threadIdx.x;
    const int rr = t >> 3;            // 0..31
    const int c8 = (t & 7) * 8;       // 0..56
#pragma unroll
    for (int i = 0; i < 2; ++i) {
        const int m = rr + i * 32;
        const int gm = m0 + m;
        const size_t grow = (size_t)b * 2048 + gm;
        const float s = mask[grow] ? dvl[grow] * rnorm[grow] : 0.0f;
        const s8v v = *(const s8v*)&Xb[(size_t)gm * 256 + d0 + c8];
        ushort4 lo, hi;
        float f[8];
#pragma unroll
        for (int j = 0; j < 8; ++j) {
            f[j] = b2f((unsigned short)v[j]) * s;
            tile[m][c8 + j] = f[j];
        }
        lo.x = f2b(f[0]); lo.y = f2b(f[1]); lo.z = f2b(f[2]); lo.w = f2b(f[3]);
        hi.x = f2b(f[4]); hi.y = f2b(f[5]); hi.z = f2b(f[6]); hi.w = f2b(f[7]);
        bf16* yrow = Y + (size_t)b * 2048 * 256 + (size_t)gm * 256 + d0 + c8;
        *(ushort4*)yrow = lo;
        *(ushort4*)(yrow + 4) = hi;
    }
    __syncthreads();
    bf16* Yb = Yt + (size_t)b * 256 * 2048;
    const int dd = t >> 3;            // 0..31
    const int m8 = (t & 7) * 8;
#pragma unroll
    for (int i = 0; i < 2; ++i) {
        const int d = dd + i * 32;
        ushort4 lo, hi;
        lo.x = f2b(tile[m8 + 0][d]); lo.y = f2b(tile[m8 + 1][d]);
        lo.z = f2b(tile[m8 + 2][d]); lo.w = f2b(tile[m8 + 3][d]);
        hi.x = f2b(tile[m8 + 4][d]); hi.y = f2b(tile[m8 + 5][d]);
        hi.z = f2b(tile[m8 + 6][d]); hi.w = f2b(tile[m8 + 7][d]);
        bf16* yt = Yb + (size_t)(d0 + d) * 2048 + m0 + m8;
        *(ushort4*)yt = lo;
        *(ushort4*)(yt + 4) = hi;
    }
}

// ---------------------------------------------------------------------------
// Transpose both weight matrices to bf16.
// ---------------------------------------------------------------------------
__global__ __launch_bounds__(256)
void prep_w(const float* __restrict__ W1, const float* __restrict__ W2,
            bf16* __restrict__ W1t, bf16* __restrict__ W2t)
{
    const int idx = blockIdx.x * 256 + threadIdx.x;
    const int h = idx & 255, d = idx >> 8;
    W1t[h * 256 + d] = __float2bfloat16(W1[idx]);
    W2t[h * 256 + d] = __float2bfloat16(W2[idx]);
}

extern "C" void kernel_launch(void* const* d_in, const int* in_sizes, int n_in,
                              void* d_out, int out_size, void* d_ws, size_t ws_size,
                              hipStream_t stream)
{
    (void)in_sizes; (void)n_in; (void)out_size; (void)ws_size;
    const float* X  = (const float*)d_in[0];
    const int*  msk = (const int*)d_in[1];
    const float* W1 = (const float*)d_in[2];
    const float* b1 = (const float*)d_in[3];
    const float* W2 = (const float*)d_in[4];
    const float* b2 = (const float*)d_in[5];

    // scratch inside d_out (134,217,728 B), all dead before the final GEMM:
    char* O = (char*)d_out;
    bf16* S    = (bf16*)(O);                 // 67,108,864 B  [8][2048][2048]
    bf16* Xn   = (bf16*)(O + 67108864);      //  8,388,608 B  [8][2048][256]
    bf16* Yt   = (bf16*)(O + 75497472);      //  8,388,608 B  [8][256][2048]
    bf16* agg  = (bf16*)(O + 83886080);      //  8,388,608 B  [8][2048][256]
    bf16* Hf   = (bf16*)(O + 92274688);      //  8,388,608 B  [16384][256]
    float* dvl = (float*)(O + 100663296);    //     65,536 B  [8][2048]
    bf16* W1t  = (bf16*)(O + 100728832);     //    131,072 B
    bf16* W2t  = (bf16*)(O + 100859904);     //    131,072 B
    float* part= (float*)(O + 100990976);    //  2,097,152 B  [8][2048][32]
    bf16* Y    = (bf16*)(O + 103088128);     //  8,388,608 B  [8][2048][256]
    float* rnm = (float*)(O + 111476736);    //     65,536 B  [8][2048]
    bf16* P    = (bf16*)d_ws;                //  8,388,608 B  (survives final GEMM)

    prep_w<<<256, 256, 0, stream>>>(W1, W2, W1t, W2t);
    xn_kernel<<<4096, 256, 0, stream>>>(X, Xn, rnm);

    // S = sigmoid(Xn Xn^T) bf16, + fused masked row-sum partials
    gemm_bt<0><<<dim3(16, 16, 8), 256, 0, stream>>>(
        Xn, Xn, S, 2048, 2048, 256,
        (size_t)2048 * 256, (size_t)2048 * 256, (size_t)2048 * 2048,
        nullptr, nullptr, msk, nullptr, part);

    fin_deg<<<4096, 256, 0, stream>>>(part, msk, dvl);
    ytY_kernel<<<dim3(32, 4, 8), 256, 0, stream>>>(Xn, rnm, dvl, msk, Y, Yt);

    // agg = m_i ? d_i*(S@Y + Y_i) : 0, bf16   (Y = d*m*X)
    gemm_bt<1><<<dim3(16, 2, 8), 256, 0, stream>>>(
        S, Yt, agg, 2048, 256, 2048,
        (size_t)2048 * 2048, (size_t)256 * 2048, (size_t)2048 * 256,
        Y, dvl, msk, nullptr, nullptr);

    // Hf = relu(agg @ W1 + b1)
    gemm_bt<2><<<dim3(128, 2, 1), 256, 0, stream>>>(
        agg, W1t, Hf, 16384, 256, 256, 0, 0, 0,
        nullptr, nullptr, nullptr, b1, nullptr);

    // P = Hf @ W2 + b2
    gemm_bt<3><<<dim3(128, 2, 1), 256, 0, stream>>>(
        Hf, W2t, P, 16384, 256, 256, 0, 0, 0,
        nullptr, nullptr, nullptr, b2, nullptr);

    // out = mask_r * mask_c * sigmoid(P P^T), f32
    gemm_bt<4><<<dim3(16, 16, 8), 256, 0, stream>>>(
        P, P, d_out, 2048, 2048, 256,
        (size_t)2048 * 256, (size_t)2048 * 256, (size_t)2048 * 2048,
        nullptr, nullptr, msk, nullptr, nullptr);
}

// Round 5
// 142.745 us; speedup vs baseline: 1.2853x; 1.0856x over previous
//
#include <hip/hip_runtime.h>
#include <hip/hip_bf16.h>
#include <cstdint>

using bf16 = __hip_bfloat16;
typedef __attribute__((ext_vector_type(8))) short s8v;
typedef __attribute__((ext_vector_type(4))) float f32x4;

#define DEV static __device__ __forceinline__

DEV float b2f(unsigned short u) {
    union { float f; unsigned int i; } w; w.i = ((unsigned int)u) << 16; return w.f;
}
DEV unsigned short f2b(float x) {
    __hip_bfloat16 h = __float2bfloat16(x);
    return __builtin_bit_cast(unsigned short, h);
}
DEV float sigm(float x) { return 1.0f / (1.0f + __expf(-x)); }

DEV void gload16(const void* g, void* l) {
    __builtin_amdgcn_global_load_lds(
        (const __attribute__((address_space(1))) uint32_t*)g,
        (__attribute__((address_space(3))) uint32_t*)l, 16, 0, 0);
}

// ---------------------------------------------------------------------------
// bf16 GEMM, C = A (MxK row-major) * B^T (B NxK row-major). BMxBN tile,
// BK=64, 4 waves (2x2), wave-tile (BM/2)x(BN/2), 16x16x32 MFMA, 2-phase
// dbuf LDS, XOR swizzle (phys = logical ^ ((row&7)<<4)), inverse-swizzled
// global staging source (gload_lds dest linear).
// Epilogues:
//  0: bf16 out = sigmoid(acc); + masked row-sum partials (BM=BN=128 only)
//  1: bf16 out = mask[row] ? d[row]*(acc + Yres[row,col]) : 0      (agg)
//  2: bf16 out = relu(acc + bias[col])
//  3: bf16 out = acc + bias[col]
//  4: f32  out = (mask[row]&mask[col]) ? sigmoid(acc) : 0
// ---------------------------------------------------------------------------
template<int BM, int BN, int EPI>
__global__ __launch_bounds__(256)
void gemm_bt(const bf16* __restrict__ A, const bf16* __restrict__ B,
             void* __restrict__ C, const int M, const int N, const int K,
             const size_t sA, const size_t sB, const size_t sC,
             const bf16* __restrict__ Yres, const float* __restrict__ dval,
             const int* __restrict__ mask, const float* __restrict__ bias,
             float* __restrict__ part)
{
    constexpr int MR = BM / 32;          // m-fragments per wave
    constexpr int NR = BN / 32;          // n-fragments per wave
    constexpr int NA = BM / 32;          // A staging instrs (BM*128B / 4KB)
    constexpr int NB = BN / 32;          // B staging instrs
    constexpr int TILEB = (BM + BN) * 128;  // bytes per buffer
    __shared__ char smb[2 * TILEB];

    const int b = blockIdx.z;
    const char* Ab = (const char*)(A + (size_t)b * sA);
    const char* Bb = (const char*)(B + (size_t)b * sB);
    const int bm = blockIdx.x * BM;
    const int bn = blockIdx.y * BN;
    const int tid = threadIdx.x;
    const int lane = tid & 63;
    const int wv = tid >> 6;
    const int wr = wv >> 1, wc = wv & 1;
    const int fr = lane & 15, fq = lane >> 4;
    const size_t lda = (size_t)K * 2;

    constexpr int NMAX = (NA > NB) ? NA : NB;
    size_t aOff[NMAX], bOff[NMAX];
    int ldsO[NMAX];
#pragma unroll
    for (int i = 0; i < NMAX; ++i) {
        const int local = i * 4096 + wv * 1024;
        const int myOff = local + lane * 16;
        const int row = myOff >> 7;
        const int lc = (myOff & 127) ^ ((row & 7) << 4);
        ldsO[i] = local;
        aOff[i] = (size_t)(bm + row) * lda + lc;
        bOff[i] = (size_t)(bn + row) * lda + lc;
    }

    f32x4 acc[MR][NR];
#pragma unroll
    for (int m = 0; m < MR; ++m)
#pragma unroll
        for (int n = 0; n < NR; ++n)
            acc[m][n] = (f32x4){0.f, 0.f, 0.f, 0.f};

    auto STAGE = [&](int buf, size_t kb) {
        char* base = smb + buf * TILEB;
#pragma unroll
        for (int i = 0; i < NA; ++i)
            gload16(Ab + aOff[i] + kb, base + ldsO[i]);
#pragma unroll
        for (int i = 0; i < NB; ++i)
            gload16(Bb + bOff[i] + kb, base + BM * 128 + ldsO[i]);
    };

    auto COMPUTE = [&](int buf) {
        const char* sA_ = smb + buf * TILEB;
        const char* sB_ = sA_ + BM * 128;
#pragma unroll
        for (int kk = 0; kk < 2; ++kk) {
            s8v af[MR], bfv[NR];
#pragma unroll
            for (int m = 0; m < MR; ++m) {
                const int r = wr * (BM / 2) + m * 16 + fr;
                const int pb = (r << 7) | ((kk * 64 + fq * 16) ^ ((r & 7) << 4));
                af[m] = *(const s8v*)(sA_ + pb);
            }
#pragma unroll
            for (int n = 0; n < NR; ++n) {
                const int r = wc * (BN / 2) + n * 16 + fr;
                const int pb = (r << 7) | ((kk * 64 + fq * 16) ^ ((r & 7) << 4));
                bfv[n] = *(const s8v*)(sB_ + pb);
            }
#pragma unroll
            for (int m = 0; m < MR; ++m)
#pragma unroll
                for (int n = 0; n < NR; ++n)
                    acc[m][n] = __builtin_amdgcn_mfma_f32_16x16x32_bf16(
                        af[m], bfv[n], acc[m][n], 0, 0, 0);
        }
    };

    const int NT = K >> 6;
    STAGE(0, 0);
    asm volatile("s_waitcnt vmcnt(0)" ::: "memory");
    __syncthreads();
    int cur = 0;
    for (int t = 0; t < NT - 1; ++t) {
        STAGE(cur ^ 1, (size_t)(t + 1) * 128);
        COMPUTE(cur);
        asm volatile("s_waitcnt vmcnt(0)" ::: "memory");
        __syncthreads();
        cur ^= 1;
    }
    COMPUTE(cur);

    // epilogue: C/D layout col = lane&15, row = (lane>>4)*4 + reg
    const int row0 = bm + wr * (BM / 2) + fq * 4;
    const int col0 = bn + wc * (BN / 2) + fr;

    if constexpr (EPI == 0) {
        int cm[NR];
#pragma unroll
        for (int n = 0; n < NR; ++n) cm[n] = mask[(size_t)b * N + col0 + n * 16];
#pragma unroll
        for (int m = 0; m < MR; ++m) {
            float rs[4] = {0.f, 0.f, 0.f, 0.f};
#pragma unroll
            for (int n = 0; n < NR; ++n) {
                const int col = col0 + n * 16;
#pragma unroll
                for (int r = 0; r < 4; ++r) {
                    const int row = row0 + m * 16 + r;
                    const float x = sigm(acc[m][n][r]);
                    ((bf16*)C)[(size_t)b * sC + (size_t)row * N + col] =
                        __float2bfloat16(x);
                    if (cm[n]) rs[r] += x;
                }
            }
#pragma unroll
            for (int off = 1; off < 16; off <<= 1)
#pragma unroll
                for (int r = 0; r < 4; ++r) rs[r] += __shfl_xor(rs[r], off);
            if (fr == 0) {
#pragma unroll
                for (int r = 0; r < 4; ++r)
                    part[((size_t)b * M + row0 + m * 16 + r) * 32 +
                         blockIdx.y * 2 + wc] = rs[r];
            }
        }
        return;
    }

#pragma unroll
    for (int m = 0; m < MR; ++m) {
#pragma unroll
        for (int n = 0; n < NR; ++n) {
            const int col = col0 + n * 16;
#pragma unroll
            for (int r = 0; r < 4; ++r) {
                const int row = row0 + m * 16 + r;
                const float x = acc[m][n][r];
                const size_t cidx = (size_t)b * sC + (size_t)row * N + col;
                if constexpr (EPI == 1) {
                    const float dn = dval[(size_t)b * M + row];
                    const int mn = mask[(size_t)b * M + row];
                    const float yv =
                        b2f(__builtin_bit_cast(unsigned short,
                            Yres[(size_t)b * M * N + (size_t)row * N + col]));
                    ((bf16*)C)[cidx] = __float2bfloat16(mn ? dn * (x + yv) : 0.0f);
                } else if constexpr (EPI == 2) {
                    ((bf16*)C)[cidx] = __float2bfloat16(fmaxf(x + bias[col], 0.0f));
                } else if constexpr (EPI == 3) {
                    ((bf16*)C)[cidx] = __float2bfloat16(x + bias[col]);
                } else {
                    const int mr = mask[(size_t)b * M + row];
                    const int mc = mask[(size_t)b * M + col];
                    ((float*)C)[cidx] = (mr & mc) ? sigm(x) : 0.0f;
                }
            }
        }
    }
}

// ---------------------------------------------------------------------------
// blocks [0,4096): row-normalize X -> Xn (bf16) + rnorm. One wave per row.
// blocks [4096,4352): transpose W1,W2 to bf16 (prep_w folded in).
// ---------------------------------------------------------------------------
__global__ __launch_bounds__(256)
void xn_kernel(const float* __restrict__ X, bf16* __restrict__ Xn,
               float* __restrict__ rnorm,
               const float* __restrict__ W1, const float* __restrict__ W2,
               bf16* __restrict__ W1t, bf16* __restrict__ W2t)
{
    if (blockIdx.x >= 4096) {
        const int idx = (blockIdx.x - 4096) * 256 + threadIdx.x;
        const int h = idx & 255, d = idx >> 8;
        W1t[h * 256 + d] = __float2bfloat16(W1[idx]);
        W2t[h * 256 + d] = __float2bfloat16(W2[idx]);
        return;
    }
    const int lane = threadIdx.x & 63;
    const size_t row = (size_t)blockIdx.x * 4 + (threadIdx.x >> 6);
    const float4 v = *(const float4*)&X[row * 256 + lane * 4];
    float ss = v.x * v.x + v.y * v.y + v.z * v.z + v.w * v.w;
#pragma unroll
    for (int o = 32; o; o >>= 1) ss += __shfl_xor(ss, o);
    const float nrm = fmaxf(sqrtf(ss), 1e-12f);
    const float inv = 1.0f / nrm;
    ushort4 o4;
    o4.x = f2b(v.x * inv); o4.y = f2b(v.y * inv);
    o4.z = f2b(v.z * inv); o4.w = f2b(v.w * inv);
    *(ushort4*)&Xn[row * 256 + lane * 4] = o4;
    if (lane == 0) rnorm[row] = nrm;
}

// ---------------------------------------------------------------------------
// Fused degree-finalize + Y/Yt build. Per block: 64 rows x 64 cols of Xn.
// Threads 0..63 first reduce part[row][0..31] -> deg -> dvl (written to
// global for the agg epilogue; duplicate identical writes across d0 blocks)
// and stage scale s = mask ? dvl*rnorm : 0 into LDS. Then all 256 threads:
//   Y [b][m][d] = bf16(s_m * Xn[m][d]); Yt[b][d][m] = same, transposed.
// ---------------------------------------------------------------------------
__global__ __launch_bounds__(256)
void ytY_kernel(const bf16* __restrict__ Xn, const float* __restrict__ rnorm,
                const float* __restrict__ part, const int* __restrict__ mask,
                float* __restrict__ dvl, bf16* __restrict__ Y,
                bf16* __restrict__ Yt)
{
    __shared__ float tile[64][65];
    __shared__ float dsh[64];
    const int b = blockIdx.z;
    const int m0 = blockIdx.x * 64, d0 = blockIdx.y * 64;
    const int t = threadIdx.x;

    if (t < 64) {
        const size_t grow = (size_t)b * 2048 + m0 + t;
        float s = 0.f;
#pragma unroll 8
        for (int i = 0; i < 32; ++i) s += part[grow * 32 + i];
        const float deg = mask[grow] ? (s + 1.0f) : 0.0f;
        const float dv = rsqrtf(fmaxf(deg, 1e-6f));
        dvl[grow] = dv;
        dsh[t] = mask[grow] ? dv * rnorm[grow] : 0.0f;
    }
    __syncthreads();

    const bf16* Xb = Xn + (size_t)b * 2048 * 256;
    const int rr = t >> 3;            // 0..31
    const int c8 = (t & 7) * 8;       // 0..56
#pragma unroll
    for (int i = 0; i < 2; ++i) {
        const int m = rr + i * 32;
        const int gm = m0 + m;
        const float s = dsh[m];
        const s8v v = *(const s8v*)&Xb[(size_t)gm * 256 + d0 + c8];
        ushort4 lo, hi;
        float f[8];
#pragma unroll
        for (int j = 0; j < 8; ++j) {
            f[j] = b2f((unsigned short)v[j]) * s;
            tile[m][c8 + j] = f[j];
        }
        lo.x = f2b(f[0]); lo.y = f2b(f[1]); lo.z = f2b(f[2]); lo.w = f2b(f[3]);
        hi.x = f2b(f[4]); hi.y = f2b(f[5]); hi.z = f2b(f[6]); hi.w = f2b(f[7]);
        bf16* yrow = Y + (size_t)b * 2048 * 256 + (size_t)gm * 256 + d0 + c8;
        *(ushort4*)yrow = lo;
        *(ushort4*)(yrow + 4) = hi;
    }
    __syncthreads();
    bf16* Yb = Yt + (size_t)b * 256 * 2048;
    const int dd = t >> 3;
    const int m8 = (t & 7) * 8;
#pragma unroll
    for (int i = 0; i < 2; ++i) {
        const int d = dd + i * 32;
        ushort4 lo, hi;
        lo.x = f2b(tile[m8 + 0][d]); lo.y = f2b(tile[m8 + 1][d]);
        lo.z = f2b(tile[m8 + 2][d]); lo.w = f2b(tile[m8 + 3][d]);
        hi.x = f2b(tile[m8 + 4][d]); hi.y = f2b(tile[m8 + 5][d]);
        hi.z = f2b(tile[m8 + 6][d]); hi.w = f2b(tile[m8 + 7][d]);
        bf16* yt = Yb + (size_t)(d0 + d) * 2048 + m0 + m8;
        *(ushort4*)yt = lo;
        *(ushort4*)(yt + 4) = hi;
    }
}

extern "C" void kernel_launch(void* const* d_in, const int* in_sizes, int n_in,
                              void* d_out, int out_size, void* d_ws, size_t ws_size,
                              hipStream_t stream)
{
    (void)in_sizes; (void)n_in; (void)out_size; (void)ws_size;
    const float* X  = (const float*)d_in[0];
    const int*  msk = (const int*)d_in[1];
    const float* W1 = (const float*)d_in[2];
    const float* b1 = (const float*)d_in[3];
    const float* W2 = (const float*)d_in[4];
    const float* b2 = (const float*)d_in[5];

    // scratch inside d_out (134,217,728 B), all dead before the final GEMM:
    char* O = (char*)d_out;
    bf16* S    = (bf16*)(O);                 // 67,108,864 B  [8][2048][2048]
    bf16* Xn   = (bf16*)(O + 67108864);      //  8,388,608 B  [8][2048][256]
    bf16* Yt   = (bf16*)(O + 75497472);      //  8,388,608 B  [8][256][2048]
    bf16* agg  = (bf16*)(O + 83886080);      //  8,388,608 B  [8][2048][256]
    bf16* Hf   = (bf16*)(O + 92274688);      //  8,388,608 B  [16384][256]
    float* dvl = (float*)(O + 100663296);    //     65,536 B  [8][2048]
    bf16* W1t  = (bf16*)(O + 100728832);     //    131,072 B
    bf16* W2t  = (bf16*)(O + 100859904);     //    131,072 B
    float* part= (float*)(O + 100990976);    //  2,097,152 B  [8][2048][32]
    bf16* Y    = (bf16*)(O + 103088128);     //  8,388,608 B  [8][2048][256]
    float* rnm = (float*)(O + 111476736);    //     65,536 B  [8][2048]
    bf16* P    = (bf16*)d_ws;                //  8,388,608 B  (survives final GEMM)

    xn_kernel<<<4352, 256, 0, stream>>>(X, Xn, rnm, W1, W2, W1t, W2t);

    // S = sigmoid(Xn Xn^T) bf16, + fused masked row-sum partials
    gemm_bt<128, 128, 0><<<dim3(16, 16, 8), 256, 0, stream>>>(
        Xn, Xn, S, 2048, 2048, 256,
        (size_t)2048 * 256, (size_t)2048 * 256, (size_t)2048 * 2048,
        nullptr, nullptr, msk, nullptr, part);

    // fused fin_deg + Y/Yt build
    ytY_kernel<<<dim3(32, 4, 8), 256, 0, stream>>>(
        Xn, rnm, part, msk, dvl, Y, Yt);

    // agg = m_i ? d_i*(S@Y + Y_i) : 0, bf16  (128x64 tile -> 512 blocks)
    gemm_bt<128, 64, 1><<<dim3(16, 4, 8), 256, 0, stream>>>(
        S, Yt, agg, 2048, 256, 2048,
        (size_t)2048 * 2048, (size_t)256 * 2048, (size_t)2048 * 256,
        Y, dvl, msk, nullptr, nullptr);

    // Hf = relu(agg @ W1 + b1)   (64x128 tile -> 512 blocks)
    gemm_bt<64, 128, 2><<<dim3(256, 2, 1), 256, 0, stream>>>(
        agg, W1t, Hf, 16384, 256, 256, 0, 0, 0,
        nullptr, nullptr, nullptr, b1, nullptr);

    // P = Hf @ W2 + b2
    gemm_bt<64, 128, 3><<<dim3(256, 2, 1), 256, 0, stream>>>(
        Hf, W2t, P, 16384, 256, 256, 0, 0, 0,
        nullptr, nullptr, nullptr, b2, nullptr);

    // out = mask_r * mask_c * sigmoid(P P^T), f32
    gemm_bt<128, 128, 4><<<dim3(16, 16, 8), 256, 0, stream>>>(
        P, P, d_out, 2048, 2048, 256,
        (size_t)2048 * 256, (size_t)2048 * 256, (size_t)2048 * 2048,
        nullptr, nullptr, msk, nullptr, nullptr);
}